// Round 4
// baseline (733.399 us; speedup 1.0000x reference)
//
#include <hip/hip_runtime.h>
#include <hip/hip_bf16.h>
#include <math.h>

// ---------------------------------------------------------------------------
// Workspace layout (float offsets, all 16B-aligned). OUT3 aliases OUT1.
// ---------------------------------------------------------------------------
constexpr size_t OFF_QW1  = 0;
constexpr size_t OFF_QW2  = 164;
constexpr size_t OFF_QB2  = 812;
constexpr size_t OFF_QW3  = 824;
constexpr size_t OFF_QB3  = 2768;
constexpr size_t OFF_QW4  = 2788;
constexpr size_t OFF_QB4  = 5704;
constexpr size_t OFF_QW5  = 5724;
constexpr size_t OFF_QB5  = 8640;
constexpr size_t OFF_QF1  = 8660;    // transposed [162][120]
constexpr size_t OFF_QFB1 = 28100;
constexpr size_t OFF_QF2  = 28220;   // transposed [120][84]
constexpr size_t OFF_QFB2 = 38300;
constexpr size_t OFF_QF3  = 38384;   // transposed [84][9]
constexpr size_t OFF_WEND = 39140;
constexpr size_t OFF_OUT1 = OFF_WEND;                         // [256][6][79][80]
constexpr size_t OFF_OUT2 = OFF_OUT1 + (size_t)256*6*79*80;   // [256][12][38][40]
constexpr size_t OFF_OUT3 = OFF_OUT1;                         // [256][18][18][20] (alias)

// ---------------------------------------------------------------------------
// Weight + bias fake-quantization. FC weights written TRANSPOSED ([K][M]).
// ---------------------------------------------------------------------------
__global__ void quant_prep(
    const float* w1, const float* w2, const float* b2,
    const float* w3, const float* b3, const float* w4, const float* b4,
    const float* w5, const float* b5, const float* fw1, const float* fb1,
    const float* fw2, const float* fb2, const float* fw3,
    const float* s1, const float* s2, const float* s3,
    const float* s4, const float* s5, const float* s6,
    float* ws)
{
    const int b = blockIdx.x;
    const float* W[8]  = {w1, w2, w3, w4, w5, fw1, fw2, fw3};
    const int    NWv[8] = {162, 648, 1944, 2916, 2916, 19440, 10080, 756};
    float* WQ[8] = {ws+OFF_QW1, ws+OFF_QW2, ws+OFF_QW3, ws+OFF_QW4,
                    ws+OFF_QW5, ws+OFF_QF1, ws+OFF_QF2, ws+OFF_QF3};
    const float* B[8]  = {nullptr, b2, b3, b4, b5, fb1, fb2, nullptr};
    const int    NB[8] = {0, 12, 18, 18, 18, 120, 84, 0};
    float* BQ[8] = {nullptr, ws+OFF_QB2, ws+OFF_QB3, ws+OFF_QB4,
                    ws+OFF_QB5, ws+OFF_QFB1, ws+OFF_QFB2, nullptr};
    const float* SP[8] = {nullptr, s1, s2, s3, s4, s5, s6, nullptr};
    const int    MM[8] = {0, 0, 0, 0, 0, 120, 84, 9};    // fc: transpose
    const int    KK[8] = {1, 1, 1, 1, 1, 162, 120, 84};

    const float* w = W[b];
    const int nw = NWv[b];

    float mx = 0.0f;
    for (int i = threadIdx.x; i < nw; i += blockDim.x)
        mx = fmaxf(mx, fabsf(w[i]));
    __shared__ float red[256];
    red[threadIdx.x] = mx;
    __syncthreads();
    for (int s = 128; s > 0; s >>= 1) {
        if ((int)threadIdx.x < s)
            red[threadIdx.x] = fmaxf(red[threadIdx.x], red[threadIdx.x + s]);
        __syncthreads();
    }
    const float sw = red[0] / 3.0f;

    float* wq = WQ[b];
    for (int i = threadIdx.x; i < nw; i += blockDim.x) {
        float q = rintf(w[i] / sw);
        q = fminf(fmaxf(q, -3.0f), 3.0f);
        const float val = q * sw;
        if (MM[b]) {
            const int m = i / KK[b];
            const int k = i - m * KK[b];
            wq[k * MM[b] + m] = val;
        } else {
            wq[i] = val;
        }
    }
    if (B[b] != nullptr) {
        const float sb = sw * (SP[b][0] / 15.0f);
        for (int i = threadIdx.x; i < NB[b]; i += blockDim.x)
            BQ[b][i] = rintf(B[b][i] / sb) * sb;
    }
}

// 16B-unit XOR swizzle: spreads the 64B-stride tile pattern across banks.
__device__ __forceinline__ int swzf4(int i, bool en) {
    return en ? (i ^ ((2 * (i >> 3)) & 6)) : i;
}

// ---------------------------------------------------------------------------
// Fused conv3x3(VALID)+bias+quant_relu+maxpool2.
// Thread = (cog, xg, ry): 3 output channels x 4 pooled cols x 1 pooled row.
// Input slab (2*RB+2 rows, all CIN channels) + weights staged in LDS.
// Row reads are 3x float4 (swizzled); same rows feed 3 co's accumulators.
// ---------------------------------------------------------------------------
template<int CIN, int COUT, int NCOG, int HIN, int WSIN,
         int HPOOL, int WPOOL, int WSOUT, int XG, int RB,
         int THREADS, bool HAS_BIAS, bool SWZ>
__global__ __launch_bounds__(THREADS, 4)
void conv_stage(const float* __restrict__ in,
                const float* __restrict__ qw,
                const float* __restrict__ qb,
                const float* __restrict__ s_act,
                float* __restrict__ out)
{
    constexpr int ROWS  = 2 * RB + 2;
    constexpr int W4IN  = WSIN / 4;
    constexpr int MAXF4 = (W4IN - 1) > 2 * XG ? (W4IN - 1) : 2 * XG;
    constexpr int WF4   = SWZ ? (MAXF4 / 8 + 1) * 8 : MAXF4 + 2;
    constexpr int WROW  = 4 * WF4;
    constexpr int NW    = COUT * CIN * 9;
    static_assert(3 * NCOG == COUT, "3 co per thread");
    static_assert(NCOG * XG * RB <= THREADS, "single compute pass");
    static_assert(4 * XG == WSOUT, "full padded row coverage");
    static_assert(WSIN % 4 == 0, "vec4 fill");

    __shared__ float lin[CIN][ROWS][WROW];
    __shared__ float lw[NW];
    __shared__ float lb[COUT];

    const int r0  = blockIdx.x * RB;
    const int n   = blockIdx.y;
    const int tid = threadIdx.x;

    for (int i = tid; i < NW; i += THREADS) lw[i] = qw[i];
    if (HAS_BIAS)
        for (int i = tid; i < COUT; i += THREADS) lb[i] = qb[i];

    const float* inN = in + (size_t)n * CIN * HIN * WSIN;
    for (int idx = tid; idx < CIN * ROWS * W4IN; idx += THREADS) {
        const int c   = idx / (ROWS * W4IN);
        const int rem = idx - c * (ROWS * W4IN);
        const int rr  = rem / W4IN;
        const int i4  = rem - rr * W4IN;
        const int grow = 2 * r0 + rr;
        if (grow < HIN)
            *(float4*)&lin[c][rr][4 * swzf4(i4, SWZ)] =
                *(const float4*)&inN[((size_t)c * HIN + grow) * WSIN + 4 * i4];
    }
    __syncthreads();

    const int o = tid;
    if (o < NCOG * XG * RB) {
        const int cog = o % NCOG;
        const int xg  = (o / NCOG) % XG;
        const int ry  = o / (NCOG * XG);

        const int p0 = 4 * swzf4(2 * xg,     SWZ);
        const int p1 = 4 * swzf4(2 * xg + 1, SWZ);
        const int p2 = 4 * swzf4(2 * xg + 2, SWZ);

        float acc[3][16];   // [co][conv-row(2) x 8 conv cols]
#pragma unroll
        for (int j = 0; j < 3; ++j)
#pragma unroll
            for (int i = 0; i < 16; ++i) acc[j][i] = 0.0f;

        for (int c = 0; c < CIN; ++c) {
            float wv[3][9];
#pragma unroll
            for (int j = 0; j < 3; ++j)
#pragma unroll
                for (int k = 0; k < 9; ++k)
                    wv[j][k] = lw[((3 * cog + j) * CIN + c) * 9 + k];

#pragma unroll
            for (int rr = 0; rr < 4; ++rr) {
                const float* lrow = &lin[c][2 * ry + rr][0];
                float4 rv[3];
                rv[0] = *(const float4*)&lrow[p0];
                rv[1] = *(const float4*)&lrow[p1];
                rv[2] = *(const float4*)&lrow[p2];
                const float* row = (const float*)rv;   // 12 floats

                if (rr < 3) {
#pragma unroll
                    for (int j = 0; j < 3; ++j)
#pragma unroll
                        for (int kc = 0; kc < 3; ++kc)
#pragma unroll
                            for (int xx = 0; xx < 8; ++xx)
                                acc[j][xx] = fmaf(row[xx + kc], wv[j][rr * 3 + kc], acc[j][xx]);
                }
                if (rr >= 1) {
#pragma unroll
                    for (int j = 0; j < 3; ++j)
#pragma unroll
                        for (int kc = 0; kc < 3; ++kc)
#pragma unroll
                            for (int xx = 0; xx < 8; ++xx)
                                acc[j][8 + xx] = fmaf(row[xx + kc], wv[j][(rr - 1) * 3 + kc], acc[j][8 + xx]);
                }
            }
        }

        const int r = r0 + ry;
        if (r < HPOOL) {
            const float step = s_act[0] / 15.0f;
#pragma unroll
            for (int j = 0; j < 3; ++j) {
                const int co = 3 * cog + j;
                const float bias = HAS_BIAS ? lb[co] : 0.0f;
                float4 st;
#pragma unroll
                for (int t = 0; t < 4; ++t) {
                    float m = fmaxf(fmaxf(acc[j][2 * t], acc[j][2 * t + 1]),
                                    fmaxf(acc[j][8 + 2 * t], acc[j][8 + 2 * t + 1]));
                    float v = fmaxf(m + bias, 0.0f);
                    float q = rintf(v / step);
                    q = fminf(fmaxf(q, 0.0f), 15.0f);
                    ((float*)&st)[t] = (4 * xg + t < WPOOL) ? q * step : 0.0f;
                }
                *(float4*)&out[(((size_t)n * COUT + co) * HPOOL + r) * WSOUT + 4 * xg] = st;
            }
        }
    }
}

// ---------------------------------------------------------------------------
// Fused tail: stage4 conv + stage5 conv + fc1 + fc2 + fc3. One block / image.
// ---------------------------------------------------------------------------
__global__ __launch_bounds__(256)
void tail_stage(const float* __restrict__ in3,   // [256][18][18][20]
                const float* __restrict__ ws,
                const float* __restrict__ s4, const float* __restrict__ s5,
                const float* __restrict__ s6, const float* __restrict__ s7,
                float* __restrict__ out)
{
    __shared__ float A[18][18][20];
    __shared__ float W4[2916], W5[2916];
    __shared__ float B4[18], B5[18];
    __shared__ float O4[18][8][8];
    __shared__ float A5[162], A6[120], A7[84];

    const int n   = blockIdx.x;
    const int tid = threadIdx.x;

    const float4* src = (const float4*)(in3 + (size_t)n * 6480);
    float4* dstA = (float4*)&A[0][0][0];
    for (int i = tid; i < 1620; i += 256) dstA[i] = src[i];
    const float* qw4 = ws + OFF_QW4;
    const float* qw5 = ws + OFF_QW5;
    for (int i = tid; i < 2916; i += 256) { W4[i] = qw4[i]; W5[i] = qw5[i]; }
    if (tid < 18) { B4[tid] = (ws + OFF_QB4)[tid]; B5[tid] = (ws + OFF_QB5)[tid]; }
    __syncthreads();

    // ---- stage 4: [18,18,18] -> [18,8,8] ----
    {
        const float step = s4[0] / 15.0f;
        for (int o = tid; o < 18 * 64; o += 256) {
            const int co = o >> 6;
            const int r  = (o >> 3) & 7;
            const int x  = o & 7;
            float a00 = 0.f, a01 = 0.f, a10 = 0.f, a11 = 0.f;
            for (int c = 0; c < 18; ++c) {
                float win[4][4];
#pragma unroll
                for (int rr = 0; rr < 4; ++rr)
#pragma unroll
                    for (int cc = 0; cc < 4; ++cc)
                        win[rr][cc] = A[c][2 * r + rr][2 * x + cc];
                const float* wp = &W4[(co * 18 + c) * 9];
#pragma unroll
                for (int kr = 0; kr < 3; ++kr)
#pragma unroll
                    for (int kc = 0; kc < 3; ++kc) {
                        const float wv = wp[kr * 3 + kc];
                        a00 = fmaf(win[kr    ][kc    ], wv, a00);
                        a01 = fmaf(win[kr    ][kc + 1], wv, a01);
                        a10 = fmaf(win[kr + 1][kc    ], wv, a10);
                        a11 = fmaf(win[kr + 1][kc + 1], wv, a11);
                    }
            }
            float m = fmaxf(fmaxf(a00, a01), fmaxf(a10, a11));
            float v = fmaxf(m + B4[co], 0.0f);
            float q = rintf(v / step);
            q = fminf(fmaxf(q, 0.0f), 15.0f);
            O4[co][r][x] = q * step;
        }
    }
    __syncthreads();

    // ---- stage 5: [18,8,8] -> [18,3,3] = A5[162] ----
    {
        const float step = s5[0] / 15.0f;
        if (tid < 162) {
            const int co = tid / 9;
            const int rem = tid - co * 9;
            const int r = rem / 3;
            const int x = rem - r * 3;
            float a00 = 0.f, a01 = 0.f, a10 = 0.f, a11 = 0.f;
            for (int c = 0; c < 18; ++c) {
                float win[4][4];
#pragma unroll
                for (int rr = 0; rr < 4; ++rr)
#pragma unroll
                    for (int cc = 0; cc < 4; ++cc)
                        win[rr][cc] = O4[c][2 * r + rr][2 * x + cc];
                const float* wp = &W5[(co * 18 + c) * 9];
#pragma unroll
                for (int kr = 0; kr < 3; ++kr)
#pragma unroll
                    for (int kc = 0; kc < 3; ++kc) {
                        const float wv = wp[kr * 3 + kc];
                        a00 = fmaf(win[kr    ][kc    ], wv, a00);
                        a01 = fmaf(win[kr    ][kc + 1], wv, a01);
                        a10 = fmaf(win[kr + 1][kc    ], wv, a10);
                        a11 = fmaf(win[kr + 1][kc + 1], wv, a11);
                    }
            }
            float m = fmaxf(fmaxf(a00, a01), fmaxf(a10, a11));
            float v = fmaxf(m + B5[co], 0.0f);
            float q = rintf(v / step);
            q = fminf(fmaxf(q, 0.0f), 15.0f);
            A5[tid] = q * step;
        }
    }
    __syncthreads();

    // ---- fc1: [162] -> [120], quant s6 ----
    {
        const float* w = ws + OFF_QF1;    // [162][120]
        if (tid < 120) {
            float acc = 0.f;
#pragma unroll 6
            for (int k = 0; k < 162; ++k)
                acc = fmaf(A5[k], w[k * 120 + tid], acc);
            acc += (ws + OFF_QFB1)[tid];
            const float step = s6[0] / 15.0f;
            float q = rintf(fmaxf(acc, 0.0f) / step);
            q = fminf(fmaxf(q, 0.0f), 15.0f);
            A6[tid] = q * step;
        }
    }
    __syncthreads();

    // ---- fc2: [120] -> [84], quant s7 ----
    {
        const float* w = ws + OFF_QF2;    // [120][84]
        if (tid < 84) {
            float acc = 0.f;
#pragma unroll 6
            for (int k = 0; k < 120; ++k)
                acc = fmaf(A6[k], w[k * 84 + tid], acc);
            acc += (ws + OFF_QFB2)[tid];
            const float step = s7[0] / 15.0f;
            float q = rintf(fmaxf(acc, 0.0f) / step);
            q = fminf(fmaxf(q, 0.0f), 15.0f);
            A7[tid] = q * step;
        }
    }
    __syncthreads();

    // ---- fc3: [84] -> [9] ----
    {
        const float* w = ws + OFF_QF3;    // [84][9]
        if (tid < 9) {
            float acc = 0.f;
#pragma unroll 6
            for (int k = 0; k < 84; ++k)
                acc = fmaf(A7[k], w[k * 9 + tid], acc);
            out[(size_t)n * 9 + tid] = acc;
        }
    }
}

// ---------------------------------------------------------------------------
extern "C" void kernel_launch(void* const* d_in, const int* in_sizes, int n_in,
                              void* d_out, int out_size, void* d_ws, size_t ws_size,
                              hipStream_t stream)
{
    const float* x   = (const float*)d_in[0];
    const float* w1  = (const float*)d_in[1];
    const float* w2  = (const float*)d_in[2];
    const float* b2  = (const float*)d_in[3];
    const float* w3  = (const float*)d_in[4];
    const float* b3  = (const float*)d_in[5];
    const float* w4  = (const float*)d_in[6];
    const float* b4  = (const float*)d_in[7];
    const float* w5  = (const float*)d_in[8];
    const float* b5  = (const float*)d_in[9];
    const float* fw1 = (const float*)d_in[10];
    const float* fb1 = (const float*)d_in[11];
    const float* fw2 = (const float*)d_in[12];
    const float* fb2 = (const float*)d_in[13];
    const float* fw3 = (const float*)d_in[14];
    const float* s1  = (const float*)d_in[15];
    const float* s2  = (const float*)d_in[16];
    const float* s3  = (const float*)d_in[17];
    const float* s4  = (const float*)d_in[18];
    const float* s5  = (const float*)d_in[19];
    const float* s6  = (const float*)d_in[20];
    const float* s7  = (const float*)d_in[21];

    float* ws = (float*)d_ws;
    float* out = (float*)d_out;

    quant_prep<<<8, 256, 0, stream>>>(w1, w2, b2, w3, b3, w4, b4, w5, b5,
                                      fw1, fb1, fw2, fb2, fw3,
                                      s1, s2, s3, s4, s5, s6, ws);

    // stage 1: [256,3,160,160] -> [256,6,79,80p]; NCOG=2 XG=20 RB=6, 256 thr
    conv_stage<3, 6, 2, 160, 160, 79, 79, 80, 20, 6, 256, false, true>
        <<<dim3(14, 256), 256, 0, stream>>>(x, ws + OFF_QW1, nullptr, s1, ws + OFF_OUT1);

    // stage 2: -> [256,12,38,40p]; NCOG=4 XG=10 RB=6, 256 thr
    conv_stage<6, 12, 4, 79, 80, 38, 38, 40, 10, 6, 256, true, true>
        <<<dim3(7, 256), 256, 0, stream>>>(ws + OFF_OUT1, ws + OFF_QW2, ws + OFF_QB2, s2, ws + OFF_OUT2);

    // stage 3: -> [256,18,18,20p]; NCOG=6 XG=5 RB=6, 192 thr (no swizzle needed)
    conv_stage<12, 18, 6, 38, 40, 18, 18, 20, 5, 6, 192, true, false>
        <<<dim3(3, 256), 192, 0, stream>>>(ws + OFF_OUT2, ws + OFF_QW3, ws + OFF_QB3, s3, ws + OFF_OUT3);

    // fused tail: stage4 + stage5 + fc1 + fc2 + fc3, one block per image
    tail_stage<<<256, 256, 0, stream>>>(ws + OFF_OUT3, ws, s4, s5, s6, s7, out);
}

// Round 5
// 270.766 us; speedup vs baseline: 2.7086x; 2.7086x over previous
//
#include <hip/hip_runtime.h>
#include <hip/hip_bf16.h>
#include <math.h>

// ---------------------------------------------------------------------------
// Workspace layout (float offsets, all 16B-aligned). OUT3 aliases OUT1.
// ---------------------------------------------------------------------------
constexpr size_t OFF_QW1  = 0;
constexpr size_t OFF_QW2  = 164;
constexpr size_t OFF_QB2  = 812;
constexpr size_t OFF_QW3  = 824;
constexpr size_t OFF_QB3  = 2768;
constexpr size_t OFF_QW4  = 2788;
constexpr size_t OFF_QB4  = 5704;
constexpr size_t OFF_QW5  = 5724;
constexpr size_t OFF_QB5  = 8640;
constexpr size_t OFF_QF1  = 8660;    // transposed [162][120]
constexpr size_t OFF_QFB1 = 28100;
constexpr size_t OFF_QF2  = 28220;   // transposed [120][84]
constexpr size_t OFF_QFB2 = 38300;
constexpr size_t OFF_QF3  = 38384;   // transposed [84][9]
constexpr size_t OFF_WEND = 39140;
constexpr size_t OFF_OUT1 = OFF_WEND;                         // [256][6][79][80]
constexpr size_t OFF_OUT2 = OFF_OUT1 + (size_t)256*6*79*80;   // [256][12][38][40]
constexpr size_t OFF_OUT3 = OFF_OUT1;                         // [256][18][18][20] (alias)

// ---------------------------------------------------------------------------
// Weight + bias fake-quantization. FC weights written TRANSPOSED ([K][M]).
// ---------------------------------------------------------------------------
__global__ void quant_prep(
    const float* w1, const float* w2, const float* b2,
    const float* w3, const float* b3, const float* w4, const float* b4,
    const float* w5, const float* b5, const float* fw1, const float* fb1,
    const float* fw2, const float* fb2, const float* fw3,
    const float* s1, const float* s2, const float* s3,
    const float* s4, const float* s5, const float* s6,
    float* ws)
{
    const int b = blockIdx.x;
    const float* W[8]  = {w1, w2, w3, w4, w5, fw1, fw2, fw3};
    const int    NWv[8] = {162, 648, 1944, 2916, 2916, 19440, 10080, 756};
    float* WQ[8] = {ws+OFF_QW1, ws+OFF_QW2, ws+OFF_QW3, ws+OFF_QW4,
                    ws+OFF_QW5, ws+OFF_QF1, ws+OFF_QF2, ws+OFF_QF3};
    const float* B[8]  = {nullptr, b2, b3, b4, b5, fb1, fb2, nullptr};
    const int    NB[8] = {0, 12, 18, 18, 18, 120, 84, 0};
    float* BQ[8] = {nullptr, ws+OFF_QB2, ws+OFF_QB3, ws+OFF_QB4,
                    ws+OFF_QB5, ws+OFF_QFB1, ws+OFF_QFB2, nullptr};
    const float* SP[8] = {nullptr, s1, s2, s3, s4, s5, s6, nullptr};
    const int    MM[8] = {0, 0, 0, 0, 0, 120, 84, 9};    // fc: transpose
    const int    KK[8] = {1, 1, 1, 1, 1, 162, 120, 84};

    const float* w = W[b];
    const int nw = NWv[b];

    float mx = 0.0f;
    for (int i = threadIdx.x; i < nw; i += blockDim.x)
        mx = fmaxf(mx, fabsf(w[i]));
    __shared__ float red[256];
    red[threadIdx.x] = mx;
    __syncthreads();
    for (int s = 128; s > 0; s >>= 1) {
        if ((int)threadIdx.x < s)
            red[threadIdx.x] = fmaxf(red[threadIdx.x], red[threadIdx.x + s]);
        __syncthreads();
    }
    const float sw = red[0] / 3.0f;

    float* wq = WQ[b];
    for (int i = threadIdx.x; i < nw; i += blockDim.x) {
        float q = rintf(w[i] / sw);
        q = fminf(fmaxf(q, -3.0f), 3.0f);
        const float val = q * sw;
        if (MM[b]) {
            const int m = i / KK[b];
            const int k = i - m * KK[b];
            wq[k * MM[b] + m] = val;
        } else {
            wq[i] = val;
        }
    }
    if (B[b] != nullptr) {
        const float sb = sw * (SP[b][0] / 15.0f);
        for (int i = threadIdx.x; i < NB[b]; i += blockDim.x)
            BQ[b][i] = rintf(B[b][i] / sb) * sb;
    }
}

// Bijective per-row bank swizzle on 16B units: folds high f4 bits AND the
// slab row into the bank-group bits. Stays within an 8-aligned block.
__device__ __forceinline__ int swzf4(int i, int row) {
    return i ^ (((i >> 3) ^ row) & 7);
}

// ---------------------------------------------------------------------------
// Fused conv3x3(VALID)+bias+quant_relu+maxpool2.
// Thread = (cog, xg, ry): 3 output channels x 4 pooled cols x 1 pooled row.
// Input slab (2*RB+2 rows, all CIN channels) + weights staged in LDS.
// ---------------------------------------------------------------------------
template<int CIN, int COUT, int NCOG, int HIN, int WSIN,
         int HPOOL, int WPOOL, int WSOUT, int XG, int RB,
         int THREADS, bool HAS_BIAS>
__global__ __launch_bounds__(THREADS)
void conv_stage(const float* __restrict__ in,
                const float* __restrict__ qw,
                const float* __restrict__ qb,
                const float* __restrict__ s_act,
                float* __restrict__ out)
{
    constexpr int ROWS = 2 * RB + 2;
    constexpr int W4IN = WSIN / 4;
    constexpr int NEED = (2 * XG + 1 > W4IN) ? (2 * XG + 1) : W4IN;
    constexpr int WF4  = ((NEED + 7) / 8) * 8;
    constexpr int WROW = 4 * WF4;
    constexpr int NW   = COUT * CIN * 9;
    static_assert(3 * NCOG == COUT, "3 co per thread");
    static_assert(NCOG * XG * RB <= THREADS, "single compute pass");
    static_assert(4 * XG == WSOUT, "full padded row coverage");
    static_assert(WSIN % 4 == 0, "vec4 fill");

    __shared__ float lin[CIN][ROWS][WROW];
    __shared__ float lw[NW];
    __shared__ float lb[COUT];

    const int r0  = blockIdx.x * RB;
    const int n   = blockIdx.y;
    const int tid = threadIdx.x;

    for (int i = tid; i < NW; i += THREADS) lw[i] = qw[i];
    if (HAS_BIAS)
        for (int i = tid; i < COUT; i += THREADS) lb[i] = qb[i];

    const float* inN = in + (size_t)n * CIN * HIN * WSIN;
    for (int idx = tid; idx < CIN * ROWS * W4IN; idx += THREADS) {
        const int c   = idx / (ROWS * W4IN);
        const int rem = idx - c * (ROWS * W4IN);
        const int rr  = rem / W4IN;
        const int i4  = rem - rr * W4IN;
        const int grow = 2 * r0 + rr;
        if (grow < HIN)
            *(float4*)&lin[c][rr][4 * swzf4(i4, rr)] =
                *(const float4*)&inN[((size_t)c * HIN + grow) * WSIN + 4 * i4];
    }
    __syncthreads();

    const int o = tid;
    if (o < NCOG * XG * RB) {
        const int cog = o % NCOG;
        const int xg  = (o / NCOG) % XG;
        const int ry  = o / (NCOG * XG);

        // c-invariant swizzled row offsets (floats within one channel plane)
        int poff[4][3];
#pragma unroll
        for (int rr = 0; rr < 4; ++rr) {
            const int row = 2 * ry + rr;
#pragma unroll
            for (int j = 0; j < 3; ++j)
                poff[rr][j] = row * WROW + 4 * swzf4(2 * xg + j, row);
        }

        float acc[3][16];   // [co][conv-row(2) x 8 conv cols]
#pragma unroll
        for (int j = 0; j < 3; ++j)
#pragma unroll
            for (int i = 0; i < 16; ++i) acc[j][i] = 0.0f;

        for (int c = 0; c < CIN; ++c) {
            const float* plane = &lin[c][0][0];
            float wv[3][9];
#pragma unroll
            for (int j = 0; j < 3; ++j)
#pragma unroll
                for (int k = 0; k < 9; ++k)
                    wv[j][k] = lw[((3 * cog + j) * CIN + c) * 9 + k];

#pragma unroll
            for (int rr = 0; rr < 4; ++rr) {
                float4 rv[3];
                rv[0] = *(const float4*)&plane[poff[rr][0]];
                rv[1] = *(const float4*)&plane[poff[rr][1]];
                rv[2] = *(const float4*)&plane[poff[rr][2]];
                const float* row = (const float*)rv;   // 12 floats

                if (rr < 3) {
#pragma unroll
                    for (int j = 0; j < 3; ++j)
#pragma unroll
                        for (int kc = 0; kc < 3; ++kc)
#pragma unroll
                            for (int xx = 0; xx < 8; ++xx)
                                acc[j][xx] = fmaf(row[xx + kc], wv[j][rr * 3 + kc], acc[j][xx]);
                }
                if (rr >= 1) {
#pragma unroll
                    for (int j = 0; j < 3; ++j)
#pragma unroll
                        for (int kc = 0; kc < 3; ++kc)
#pragma unroll
                            for (int xx = 0; xx < 8; ++xx)
                                acc[j][8 + xx] = fmaf(row[xx + kc], wv[j][(rr - 1) * 3 + kc], acc[j][8 + xx]);
                }
            }
        }

        const int r = r0 + ry;
        if (r < HPOOL) {
            const float step = s_act[0] / 15.0f;
#pragma unroll
            for (int j = 0; j < 3; ++j) {
                const int co = 3 * cog + j;
                const float bias = HAS_BIAS ? lb[co] : 0.0f;
                float4 st;
#pragma unroll
                for (int t = 0; t < 4; ++t) {
                    float m = fmaxf(fmaxf(acc[j][2 * t], acc[j][2 * t + 1]),
                                    fmaxf(acc[j][8 + 2 * t], acc[j][8 + 2 * t + 1]));
                    float v = fmaxf(m + bias, 0.0f);
                    float q = rintf(v / step);
                    q = fminf(fmaxf(q, 0.0f), 15.0f);
                    ((float*)&st)[t] = (4 * xg + t < WPOOL) ? q * step : 0.0f;
                }
                *(float4*)&out[(((size_t)n * COUT + co) * HPOOL + r) * WSOUT + 4 * xg] = st;
            }
        }
    }
}

// ---------------------------------------------------------------------------
// Fused tail: stage4 conv + stage5 conv + fc1 + fc2 + fc3. One block / image.
// ---------------------------------------------------------------------------
__global__ __launch_bounds__(256)
void tail_stage(const float* __restrict__ in3,   // [256][18][18][20]
                const float* __restrict__ ws,
                const float* __restrict__ s4, const float* __restrict__ s5,
                const float* __restrict__ s6, const float* __restrict__ s7,
                float* __restrict__ out)
{
    __shared__ float A[18][18][20];
    __shared__ float W4[2916], W5[2916];
    __shared__ float B4[18], B5[18];
    __shared__ float O4[18][8][8];
    __shared__ float A5[162], A6[120], A7[84];

    const int n   = blockIdx.x;
    const int tid = threadIdx.x;

    const float4* src = (const float4*)(in3 + (size_t)n * 6480);
    float4* dstA = (float4*)&A[0][0][0];
    for (int i = tid; i < 1620; i += 256) dstA[i] = src[i];
    const float* qw4 = ws + OFF_QW4;
    const float* qw5 = ws + OFF_QW5;
    for (int i = tid; i < 2916; i += 256) { W4[i] = qw4[i]; W5[i] = qw5[i]; }
    if (tid < 18) { B4[tid] = (ws + OFF_QB4)[tid]; B5[tid] = (ws + OFF_QB5)[tid]; }
    __syncthreads();

    // ---- stage 4: [18,18,18] -> [18,8,8] ----
    {
        const float step = s4[0] / 15.0f;
        for (int o = tid; o < 18 * 64; o += 256) {
            const int co = o >> 6;
            const int r  = (o >> 3) & 7;
            const int x  = o & 7;
            float a00 = 0.f, a01 = 0.f, a10 = 0.f, a11 = 0.f;
            for (int c = 0; c < 18; ++c) {
                float win[4][4];
#pragma unroll
                for (int rr = 0; rr < 4; ++rr)
#pragma unroll
                    for (int cc = 0; cc < 4; ++cc)
                        win[rr][cc] = A[c][2 * r + rr][2 * x + cc];
                const float* wp = &W4[(co * 18 + c) * 9];
#pragma unroll
                for (int kr = 0; kr < 3; ++kr)
#pragma unroll
                    for (int kc = 0; kc < 3; ++kc) {
                        const float wv = wp[kr * 3 + kc];
                        a00 = fmaf(win[kr    ][kc    ], wv, a00);
                        a01 = fmaf(win[kr    ][kc + 1], wv, a01);
                        a10 = fmaf(win[kr + 1][kc    ], wv, a10);
                        a11 = fmaf(win[kr + 1][kc + 1], wv, a11);
                    }
            }
            float m = fmaxf(fmaxf(a00, a01), fmaxf(a10, a11));
            float v = fmaxf(m + B4[co], 0.0f);
            float q = rintf(v / step);
            q = fminf(fmaxf(q, 0.0f), 15.0f);
            O4[co][r][x] = q * step;
        }
    }
    __syncthreads();

    // ---- stage 5: [18,8,8] -> [18,3,3] = A5[162] ----
    {
        const float step = s5[0] / 15.0f;
        if (tid < 162) {
            const int co = tid / 9;
            const int rem = tid - co * 9;
            const int r = rem / 3;
            const int x = rem - r * 3;
            float a00 = 0.f, a01 = 0.f, a10 = 0.f, a11 = 0.f;
            for (int c = 0; c < 18; ++c) {
                float win[4][4];
#pragma unroll
                for (int rr = 0; rr < 4; ++rr)
#pragma unroll
                    for (int cc = 0; cc < 4; ++cc)
                        win[rr][cc] = O4[c][2 * r + rr][2 * x + cc];
                const float* wp = &W5[(co * 18 + c) * 9];
#pragma unroll
                for (int kr = 0; kr < 3; ++kr)
#pragma unroll
                    for (int kc = 0; kc < 3; ++kc) {
                        const float wv = wp[kr * 3 + kc];
                        a00 = fmaf(win[kr    ][kc    ], wv, a00);
                        a01 = fmaf(win[kr    ][kc + 1], wv, a01);
                        a10 = fmaf(win[kr + 1][kc    ], wv, a10);
                        a11 = fmaf(win[kr + 1][kc + 1], wv, a11);
                    }
            }
            float m = fmaxf(fmaxf(a00, a01), fmaxf(a10, a11));
            float v = fmaxf(m + B5[co], 0.0f);
            float q = rintf(v / step);
            q = fminf(fmaxf(q, 0.0f), 15.0f);
            A5[tid] = q * step;
        }
    }
    __syncthreads();

    // ---- fc1: [162] -> [120], quant s6 ----
    {
        const float* w = ws + OFF_QF1;    // [162][120]
        if (tid < 120) {
            float acc = 0.f;
#pragma unroll 6
            for (int k = 0; k < 162; ++k)
                acc = fmaf(A5[k], w[k * 120 + tid], acc);
            acc += (ws + OFF_QFB1)[tid];
            const float step = s6[0] / 15.0f;
            float q = rintf(fmaxf(acc, 0.0f) / step);
            q = fminf(fmaxf(q, 0.0f), 15.0f);
            A6[tid] = q * step;
        }
    }
    __syncthreads();

    // ---- fc2: [120] -> [84], quant s7 ----
    {
        const float* w = ws + OFF_QF2;    // [120][84]
        if (tid < 84) {
            float acc = 0.f;
#pragma unroll 6
            for (int k = 0; k < 120; ++k)
                acc = fmaf(A6[k], w[k * 84 + tid], acc);
            acc += (ws + OFF_QFB2)[tid];
            const float step = s7[0] / 15.0f;
            float q = rintf(fmaxf(acc, 0.0f) / step);
            q = fminf(fmaxf(q, 0.0f), 15.0f);
            A7[tid] = q * step;
        }
    }
    __syncthreads();

    // ---- fc3: [84] -> [9] ----
    {
        const float* w = ws + OFF_QF3;    // [84][9]
        if (tid < 9) {
            float acc = 0.f;
#pragma unroll 6
            for (int k = 0; k < 84; ++k)
                acc = fmaf(A7[k], w[k * 9 + tid], acc);
            out[(size_t)n * 9 + tid] = acc;
        }
    }
}

// ---------------------------------------------------------------------------
extern "C" void kernel_launch(void* const* d_in, const int* in_sizes, int n_in,
                              void* d_out, int out_size, void* d_ws, size_t ws_size,
                              hipStream_t stream)
{
    const float* x   = (const float*)d_in[0];
    const float* w1  = (const float*)d_in[1];
    const float* w2  = (const float*)d_in[2];
    const float* b2  = (const float*)d_in[3];
    const float* w3  = (const float*)d_in[4];
    const float* b3  = (const float*)d_in[5];
    const float* w4  = (const float*)d_in[6];
    const float* b4  = (const float*)d_in[7];
    const float* w5  = (const float*)d_in[8];
    const float* b5  = (const float*)d_in[9];
    const float* fw1 = (const float*)d_in[10];
    const float* fb1 = (const float*)d_in[11];
    const float* fw2 = (const float*)d_in[12];
    const float* fb2 = (const float*)d_in[13];
    const float* fw3 = (const float*)d_in[14];
    const float* s1  = (const float*)d_in[15];
    const float* s2  = (const float*)d_in[16];
    const float* s3  = (const float*)d_in[17];
    const float* s4  = (const float*)d_in[18];
    const float* s5  = (const float*)d_in[19];
    const float* s6  = (const float*)d_in[20];
    const float* s7  = (const float*)d_in[21];

    float* ws = (float*)d_ws;
    float* out = (float*)d_out;

    quant_prep<<<8, 256, 0, stream>>>(w1, w2, b2, w3, b3, w4, b4, w5, b5,
                                      fw1, fb1, fw2, fb2, fw3,
                                      s1, s2, s3, s4, s5, s6, ws);

    // stage 1: [256,3,160,160] -> [256,6,79,80p]; NCOG=2 XG=20 RB=6, 256 thr
    conv_stage<3, 6, 2, 160, 160, 79, 79, 80, 20, 6, 256, false>
        <<<dim3(14, 256), 256, 0, stream>>>(x, ws + OFF_QW1, nullptr, s1, ws + OFF_OUT1);

    // stage 2: -> [256,12,38,40p]; NCOG=4 XG=10 RB=6, 256 thr
    conv_stage<6, 12, 4, 79, 80, 38, 38, 40, 10, 6, 256, true>
        <<<dim3(7, 256), 256, 0, stream>>>(ws + OFF_OUT1, ws + OFF_QW2, ws + OFF_QB2, s2, ws + OFF_OUT2);

    // stage 3: -> [256,18,18,20p]; NCOG=6 XG=5 RB=4, 128 thr
    conv_stage<12, 18, 6, 38, 40, 18, 18, 20, 5, 4, 128, true>
        <<<dim3(5, 256), 128, 0, stream>>>(ws + OFF_OUT2, ws + OFF_QW3, ws + OFF_QB3, s3, ws + OFF_OUT3);

    // fused tail: stage4 + stage5 + fc1 + fc2 + fc3, one block per image
    tail_stage<<<256, 256, 0, stream>>>(ws + OFF_OUT3, ws, s4, s5, s6, s7, out);
}

// Round 6
// 211.840 us; speedup vs baseline: 3.4620x; 1.2782x over previous
//
#include <hip/hip_runtime.h>
#include <hip/hip_bf16.h>
#include <math.h>

// ---------------------------------------------------------------------------
// Workspace layout (float offsets, all 16B-aligned). OUT3 aliases OUT1.
// ---------------------------------------------------------------------------
constexpr size_t OFF_QW1  = 0;
constexpr size_t OFF_QW2  = 164;
constexpr size_t OFF_QB2  = 812;
constexpr size_t OFF_QW3  = 824;
constexpr size_t OFF_QB3  = 2768;
constexpr size_t OFF_QW4  = 2788;
constexpr size_t OFF_QB4  = 5704;
constexpr size_t OFF_QW5  = 5724;
constexpr size_t OFF_QB5  = 8640;
constexpr size_t OFF_QF1  = 8660;    // transposed [162][120]
constexpr size_t OFF_QFB1 = 28100;
constexpr size_t OFF_QF2  = 28220;   // transposed [120][84]
constexpr size_t OFF_QFB2 = 38300;
constexpr size_t OFF_QF3  = 38384;   // transposed [84][9]
constexpr size_t OFF_WEND = 39140;
constexpr size_t OFF_OUT1 = OFF_WEND;                         // [256][6][79][80]
constexpr size_t OFF_OUT2 = OFF_OUT1 + (size_t)256*6*79*80;   // [256][12][38][40]
constexpr size_t OFF_OUT3 = OFF_OUT1;                         // [256][18][18][20] (alias)

// ---------------------------------------------------------------------------
// Weight + bias fake-quantization. FC weights written TRANSPOSED ([K][M]).
// ---------------------------------------------------------------------------
__global__ void quant_prep(
    const float* w1, const float* w2, const float* b2,
    const float* w3, const float* b3, const float* w4, const float* b4,
    const float* w5, const float* b5, const float* fw1, const float* fb1,
    const float* fw2, const float* fb2, const float* fw3,
    const float* s1, const float* s2, const float* s3,
    const float* s4, const float* s5, const float* s6,
    float* ws)
{
    const int b = blockIdx.x;
    const float* W[8]  = {w1, w2, w3, w4, w5, fw1, fw2, fw3};
    const int    NWv[8] = {162, 648, 1944, 2916, 2916, 19440, 10080, 756};
    float* WQ[8] = {ws+OFF_QW1, ws+OFF_QW2, ws+OFF_QW3, ws+OFF_QW4,
                    ws+OFF_QW5, ws+OFF_QF1, ws+OFF_QF2, ws+OFF_QF3};
    const float* B[8]  = {nullptr, b2, b3, b4, b5, fb1, fb2, nullptr};
    const int    NB[8] = {0, 12, 18, 18, 18, 120, 84, 0};
    float* BQ[8] = {nullptr, ws+OFF_QB2, ws+OFF_QB3, ws+OFF_QB4,
                    ws+OFF_QB5, ws+OFF_QFB1, ws+OFF_QFB2, nullptr};
    const float* SP[8] = {nullptr, s1, s2, s3, s4, s5, s6, nullptr};
    const int    MM[8] = {0, 0, 0, 0, 0, 120, 84, 9};    // fc: transpose
    const int    KK[8] = {1, 1, 1, 1, 1, 162, 120, 84};

    const float* w = W[b];
    const int nw = NWv[b];

    float mx = 0.0f;
    for (int i = threadIdx.x; i < nw; i += blockDim.x)
        mx = fmaxf(mx, fabsf(w[i]));
    __shared__ float red[256];
    red[threadIdx.x] = mx;
    __syncthreads();
    for (int s = 128; s > 0; s >>= 1) {
        if ((int)threadIdx.x < s)
            red[threadIdx.x] = fmaxf(red[threadIdx.x], red[threadIdx.x + s]);
        __syncthreads();
    }
    const float sw = red[0] / 3.0f;

    float* wq = WQ[b];
    for (int i = threadIdx.x; i < nw; i += blockDim.x) {
        float q = rintf(w[i] / sw);
        q = fminf(fmaxf(q, -3.0f), 3.0f);
        const float val = q * sw;
        if (MM[b]) {
            const int m = i / KK[b];
            const int k = i - m * KK[b];
            wq[k * MM[b] + m] = val;
        } else {
            wq[i] = val;
        }
    }
    if (B[b] != nullptr) {
        const float sb = sw * (SP[b][0] / 15.0f);
        for (int i = threadIdx.x; i < NB[b]; i += blockDim.x)
            BQ[b][i] = rintf(B[b][i] / sb) * sb;
    }
}

// ---------------------------------------------------------------------------
// Fused conv3x3(VALID)+bias+quant_relu+maxpool2, direct-global-read version.
// No input LDS slab, no barriers in the hot path: 12 independent
// global_load_dwordx4 per channel iteration pipeline deeply under vmcnt.
// Thread = (cog, xg, ry): NCO output channels x 4 pooled cols x 1 pooled row.
// Rightmost float4 unit clamped to row end: clamped values only ever feed
// pooled columns >= WPOOL, which are written as 0 pad (verified per stage).
// ---------------------------------------------------------------------------
template<int CIN, int COUT, int NCO, int HIN, int WSIN,
         int HPOOL, int WPOOL, int WSOUT, int XG, int RB,
         int THREADS, bool HAS_BIAS>
__global__ __launch_bounds__(THREADS)
void conv_stage(const float* __restrict__ in,
                const float* __restrict__ qw,
                const float* __restrict__ qb,
                const float* __restrict__ s_act,
                float* __restrict__ out)
{
    constexpr int GROUPS = COUT / NCO;
    constexpr int W4IN   = WSIN / 4;
    constexpr int NW     = COUT * CIN * 9;
    static_assert(NCO * GROUPS == COUT, "NCO divides COUT");
    static_assert(GROUPS * XG * RB <= THREADS, "single compute pass");
    static_assert(4 * XG == WSOUT, "full padded row coverage");
    static_assert(WSIN % 4 == 0, "vec4 loads");

    __shared__ float lw[NW];
    __shared__ float lb[COUT];

    const int r0  = blockIdx.x * RB;
    const int n   = blockIdx.y;
    const int tid = threadIdx.x;

    for (int i = tid; i < NW; i += THREADS) lw[i] = qw[i];
    if (HAS_BIAS)
        for (int i = tid; i < COUT; i += THREADS) lb[i] = qb[i];
    __syncthreads();

    const int o = tid;
    if (o >= GROUPS * XG * RB) return;
    const int cog = o % GROUPS;
    const int xg  = (o / GROUPS) % XG;
    const int ry  = o / (GROUPS * XG);
    const int r   = r0 + ry;
    if (r >= HPOOL) return;

    const float step = s_act[0] / 15.0f;   // hoisted scalar load

    // float4 unit offsets within a row (clamped at the right edge)
    const int u0 = 2 * xg;
    const int u1 = 2 * xg + 1;
    const int u2 = (2 * xg + 2 < W4IN) ? (2 * xg + 2) : (W4IN - 1);

    // base: channel 0, input row 2r
    const float* base = in + (size_t)n * CIN * HIN * WSIN + (size_t)(2 * r) * WSIN;

    float acc[NCO][16];   // [co][conv-row(2) x 8 conv cols]
#pragma unroll
    for (int j = 0; j < NCO; ++j)
#pragma unroll
        for (int i = 0; i < 16; ++i) acc[j][i] = 0.0f;

    for (int c = 0; c < CIN; ++c) {
        const float* plane = base + (size_t)c * HIN * WSIN;
        float wv[NCO][9];
#pragma unroll
        for (int j = 0; j < NCO; ++j)
#pragma unroll
            for (int k = 0; k < 9; ++k)
                wv[j][k] = lw[((NCO * cog + j) * CIN + c) * 9 + k];

#pragma unroll
        for (int rr = 0; rr < 4; ++rr) {
            const float* rp = plane + rr * WSIN;
            float4 rv[3];
            rv[0] = *(const float4*)&rp[4 * u0];
            rv[1] = *(const float4*)&rp[4 * u1];
            rv[2] = *(const float4*)&rp[4 * u2];
            const float* row = (const float*)rv;   // 12 floats

            if (rr < 3) {
#pragma unroll
                for (int j = 0; j < NCO; ++j)
#pragma unroll
                    for (int kc = 0; kc < 3; ++kc)
#pragma unroll
                        for (int xx = 0; xx < 8; ++xx)
                            acc[j][xx] = fmaf(row[xx + kc], wv[j][rr * 3 + kc], acc[j][xx]);
            }
            if (rr >= 1) {
#pragma unroll
                for (int j = 0; j < NCO; ++j)
#pragma unroll
                    for (int kc = 0; kc < 3; ++kc)
#pragma unroll
                        for (int xx = 0; xx < 8; ++xx)
                            acc[j][8 + xx] = fmaf(row[xx + kc], wv[j][(rr - 1) * 3 + kc], acc[j][8 + xx]);
            }
        }
    }

#pragma unroll
    for (int j = 0; j < NCO; ++j) {
        const int co = NCO * cog + j;
        const float bias = HAS_BIAS ? lb[co] : 0.0f;
        float4 st;
#pragma unroll
        for (int t = 0; t < 4; ++t) {
            float m = fmaxf(fmaxf(acc[j][2 * t], acc[j][2 * t + 1]),
                            fmaxf(acc[j][8 + 2 * t], acc[j][8 + 2 * t + 1]));
            float v = fmaxf(m + bias, 0.0f);
            float q = rintf(v / step);
            q = fminf(fmaxf(q, 0.0f), 15.0f);
            ((float*)&st)[t] = (4 * xg + t < WPOOL) ? q * step : 0.0f;
        }
        *(float4*)&out[(((size_t)n * COUT + co) * HPOOL + r) * WSOUT + 4 * xg] = st;
    }
}

// ---------------------------------------------------------------------------
// Fused tail: stage4 conv + stage5 conv + fc1 + fc2 + fc3. One block / image.
// ---------------------------------------------------------------------------
__global__ __launch_bounds__(256)
void tail_stage(const float* __restrict__ in3,   // [256][18][18][20]
                const float* __restrict__ ws,
                const float* __restrict__ s4, const float* __restrict__ s5,
                const float* __restrict__ s6, const float* __restrict__ s7,
                float* __restrict__ out)
{
    __shared__ float A[18][18][20];
    __shared__ float W4[2916], W5[2916];
    __shared__ float B4[18], B5[18];
    __shared__ float O4[18][8][8];
    __shared__ float A5[162], A6[120], A7[84];

    const int n   = blockIdx.x;
    const int tid = threadIdx.x;

    const float4* src = (const float4*)(in3 + (size_t)n * 6480);
    float4* dstA = (float4*)&A[0][0][0];
    for (int i = tid; i < 1620; i += 256) dstA[i] = src[i];
    const float* qw4 = ws + OFF_QW4;
    const float* qw5 = ws + OFF_QW5;
    for (int i = tid; i < 2916; i += 256) { W4[i] = qw4[i]; W5[i] = qw5[i]; }
    if (tid < 18) { B4[tid] = (ws + OFF_QB4)[tid]; B5[tid] = (ws + OFF_QB5)[tid]; }
    __syncthreads();

    // ---- stage 4: [18,18,18] -> [18,8,8] ----
    {
        const float step = s4[0] / 15.0f;
        for (int o = tid; o < 18 * 64; o += 256) {
            const int co = o >> 6;
            const int r  = (o >> 3) & 7;
            const int x  = o & 7;
            float a00 = 0.f, a01 = 0.f, a10 = 0.f, a11 = 0.f;
            for (int c = 0; c < 18; ++c) {
                float win[4][4];
#pragma unroll
                for (int rr = 0; rr < 4; ++rr)
#pragma unroll
                    for (int cc = 0; cc < 4; ++cc)
                        win[rr][cc] = A[c][2 * r + rr][2 * x + cc];
                const float* wp = &W4[(co * 18 + c) * 9];
#pragma unroll
                for (int kr = 0; kr < 3; ++kr)
#pragma unroll
                    for (int kc = 0; kc < 3; ++kc) {
                        const float wv = wp[kr * 3 + kc];
                        a00 = fmaf(win[kr    ][kc    ], wv, a00);
                        a01 = fmaf(win[kr    ][kc + 1], wv, a01);
                        a10 = fmaf(win[kr + 1][kc    ], wv, a10);
                        a11 = fmaf(win[kr + 1][kc + 1], wv, a11);
                    }
            }
            float m = fmaxf(fmaxf(a00, a01), fmaxf(a10, a11));
            float v = fmaxf(m + B4[co], 0.0f);
            float q = rintf(v / step);
            q = fminf(fmaxf(q, 0.0f), 15.0f);
            O4[co][r][x] = q * step;
        }
    }
    __syncthreads();

    // ---- stage 5: [18,8,8] -> [18,3,3] = A5[162] ----
    {
        const float step = s5[0] / 15.0f;
        if (tid < 162) {
            const int co = tid / 9;
            const int rem = tid - co * 9;
            const int r = rem / 3;
            const int x = rem - r * 3;
            float a00 = 0.f, a01 = 0.f, a10 = 0.f, a11 = 0.f;
            for (int c = 0; c < 18; ++c) {
                float win[4][4];
#pragma unroll
                for (int rr = 0; rr < 4; ++rr)
#pragma unroll
                    for (int cc = 0; cc < 4; ++cc)
                        win[rr][cc] = O4[c][2 * r + rr][2 * x + cc];
                const float* wp = &W5[(co * 18 + c) * 9];
#pragma unroll
                for (int kr = 0; kr < 3; ++kr)
#pragma unroll
                    for (int kc = 0; kc < 3; ++kc) {
                        const float wv = wp[kr * 3 + kc];
                        a00 = fmaf(win[kr    ][kc    ], wv, a00);
                        a01 = fmaf(win[kr    ][kc + 1], wv, a01);
                        a10 = fmaf(win[kr + 1][kc    ], wv, a10);
                        a11 = fmaf(win[kr + 1][kc + 1], wv, a11);
                    }
            }
            float m = fmaxf(fmaxf(a00, a01), fmaxf(a10, a11));
            float v = fmaxf(m + B5[co], 0.0f);
            float q = rintf(v / step);
            q = fminf(fmaxf(q, 0.0f), 15.0f);
            A5[tid] = q * step;
        }
    }
    __syncthreads();

    // ---- fc1: [162] -> [120], quant s6 ----
    {
        const float* w = ws + OFF_QF1;    // [162][120]
        if (tid < 120) {
            float acc = 0.f;
#pragma unroll 6
            for (int k = 0; k < 162; ++k)
                acc = fmaf(A5[k], w[k * 120 + tid], acc);
            acc += (ws + OFF_QFB1)[tid];
            const float step = s6[0] / 15.0f;
            float q = rintf(fmaxf(acc, 0.0f) / step);
            q = fminf(fmaxf(q, 0.0f), 15.0f);
            A6[tid] = q * step;
        }
    }
    __syncthreads();

    // ---- fc2: [120] -> [84], quant s7 ----
    {
        const float* w = ws + OFF_QF2;    // [120][84]
        if (tid < 84) {
            float acc = 0.f;
#pragma unroll 6
            for (int k = 0; k < 120; ++k)
                acc = fmaf(A6[k], w[k * 84 + tid], acc);
            acc += (ws + OFF_QFB2)[tid];
            const float step = s7[0] / 15.0f;
            float q = rintf(fmaxf(acc, 0.0f) / step);
            q = fminf(fmaxf(q, 0.0f), 15.0f);
            A7[tid] = q * step;
        }
    }
    __syncthreads();

    // ---- fc3: [84] -> [9] ----
    {
        const float* w = ws + OFF_QF3;    // [84][9]
        if (tid < 9) {
            float acc = 0.f;
#pragma unroll 6
            for (int k = 0; k < 84; ++k)
                acc = fmaf(A7[k], w[k * 9 + tid], acc);
            out[(size_t)n * 9 + tid] = acc;
        }
    }
}

// ---------------------------------------------------------------------------
extern "C" void kernel_launch(void* const* d_in, const int* in_sizes, int n_in,
                              void* d_out, int out_size, void* d_ws, size_t ws_size,
                              hipStream_t stream)
{
    const float* x   = (const float*)d_in[0];
    const float* w1  = (const float*)d_in[1];
    const float* w2  = (const float*)d_in[2];
    const float* b2  = (const float*)d_in[3];
    const float* w3  = (const float*)d_in[4];
    const float* b3  = (const float*)d_in[5];
    const float* w4  = (const float*)d_in[6];
    const float* b4  = (const float*)d_in[7];
    const float* w5  = (const float*)d_in[8];
    const float* b5  = (const float*)d_in[9];
    const float* fw1 = (const float*)d_in[10];
    const float* fb1 = (const float*)d_in[11];
    const float* fw2 = (const float*)d_in[12];
    const float* fb2 = (const float*)d_in[13];
    const float* fw3 = (const float*)d_in[14];
    const float* s1  = (const float*)d_in[15];
    const float* s2  = (const float*)d_in[16];
    const float* s3  = (const float*)d_in[17];
    const float* s4  = (const float*)d_in[18];
    const float* s5  = (const float*)d_in[19];
    const float* s6  = (const float*)d_in[20];
    const float* s7  = (const float*)d_in[21];

    float* ws = (float*)d_ws;
    float* out = (float*)d_out;

    quant_prep<<<8, 256, 0, stream>>>(w1, w2, b2, w3, b3, w4, b4, w5, b5,
                                      fw1, fb1, fw2, fb2, fw3,
                                      s1, s2, s3, s4, s5, s6, ws);

    // stage 1: [256,3,160,160] -> [256,6,79,80p]; NCO=2 GROUPS=3 XG=20 RB=4
    conv_stage<3, 6, 2, 160, 160, 79, 79, 80, 20, 4, 256, false>
        <<<dim3(20, 256), 256, 0, stream>>>(x, ws + OFF_QW1, nullptr, s1, ws + OFF_OUT1);

    // stage 2: -> [256,12,38,40p]; NCO=2 GROUPS=6 XG=10 RB=4
    conv_stage<6, 12, 2, 79, 80, 38, 38, 40, 10, 4, 256, true>
        <<<dim3(10, 256), 256, 0, stream>>>(ws + OFF_OUT1, ws + OFF_QW2, ws + OFF_QB2, s2, ws + OFF_OUT2);

    // stage 3: -> [256,18,18,20p]; NCO=3 GROUPS=6 XG=5 RB=6
    conv_stage<12, 18, 3, 38, 40, 18, 18, 20, 5, 6, 192, true>
        <<<dim3(3, 256), 192, 0, stream>>>(ws + OFF_OUT2, ws + OFF_QW3, ws + OFF_QB3, s3, ws + OFF_OUT3);

    // fused tail: stage4 + stage5 + fc1 + fc2 + fc3, one block per image
    tail_stage<<<256, 256, 0, stream>>>(ws + OFF_OUT3, ws, s4, s5, s6, s7, out);
}

// Round 7
// 201.018 us; speedup vs baseline: 3.6484x; 1.0538x over previous
//
#include <hip/hip_runtime.h>
#include <hip/hip_bf16.h>
#include <math.h>

// ---------------------------------------------------------------------------
// Workspace layout (float offsets, all 16B-aligned). OUT3 aliases OUT1.
// ---------------------------------------------------------------------------
constexpr size_t OFF_QW1  = 0;
constexpr size_t OFF_QW2  = 164;
constexpr size_t OFF_QB2  = 812;
constexpr size_t OFF_QW3  = 824;
constexpr size_t OFF_QB3  = 2768;
constexpr size_t OFF_QW4  = 2788;
constexpr size_t OFF_QB4  = 5704;
constexpr size_t OFF_QW5  = 5724;
constexpr size_t OFF_QB5  = 8640;
constexpr size_t OFF_QF1  = 8660;    // transposed [162][120]
constexpr size_t OFF_QFB1 = 28100;
constexpr size_t OFF_QF2  = 28220;   // transposed [120][84]
constexpr size_t OFF_QFB2 = 38300;
constexpr size_t OFF_QF3  = 38384;   // transposed [84][9]
constexpr size_t OFF_WEND = 39140;
constexpr size_t OFF_OUT1 = OFF_WEND;                         // [256][6][79][80]
constexpr size_t OFF_OUT2 = OFF_OUT1 + (size_t)256*6*79*80;   // [256][12][38][40]
constexpr size_t OFF_OUT3 = OFF_OUT1;                         // [256][18][18][20] (alias)

// ---------------------------------------------------------------------------
// Weight + bias fake-quantization. 12 blocks: big tensors are sliced (each
// slice block redundantly computes the same max, then quantizes its slice).
// FC weights written TRANSPOSED ([K][M]).
// ---------------------------------------------------------------------------
__global__ void quant_prep(
    const float* w1, const float* w2, const float* b2,
    const float* w3, const float* b3, const float* w4, const float* b4,
    const float* w5, const float* b5, const float* fw1, const float* fb1,
    const float* fw2, const float* fb2, const float* fw3,
    const float* s1, const float* s2, const float* s3,
    const float* s4, const float* s5, const float* s6,
    float* ws)
{
    const int bid = blockIdx.x;
    const int T_[12]  = {0,1,2,3,4,5,5,5,5,6,6,7};   // tensor id
    const int SL[12]  = {0,0,0,0,0,0,1,2,3,0,1,0};   // slice index
    const int NS[12]  = {1,1,1,1,1,4,4,4,4,2,2,1};   // slices for that tensor

    const float* W[8]  = {w1, w2, w3, w4, w5, fw1, fw2, fw3};
    const int    NWv[8] = {162, 648, 1944, 2916, 2916, 19440, 10080, 756};
    float* WQ[8] = {ws+OFF_QW1, ws+OFF_QW2, ws+OFF_QW3, ws+OFF_QW4,
                    ws+OFF_QW5, ws+OFF_QF1, ws+OFF_QF2, ws+OFF_QF3};
    const float* B[8]  = {nullptr, b2, b3, b4, b5, fb1, fb2, nullptr};
    const int    NB[8] = {0, 12, 18, 18, 18, 120, 84, 0};
    float* BQ[8] = {nullptr, ws+OFF_QB2, ws+OFF_QB3, ws+OFF_QB4,
                    ws+OFF_QB5, ws+OFF_QFB1, ws+OFF_QFB2, nullptr};
    const float* SP[8] = {nullptr, s1, s2, s3, s4, s5, s6, nullptr};
    const int    MM[8] = {0, 0, 0, 0, 0, 120, 84, 9};    // fc: transpose
    const int    KK[8] = {1, 1, 1, 1, 1, 162, 120, 84};

    const int t  = T_[bid];
    const float* w = W[t];
    const int nw = NWv[t];

    float mx = 0.0f;
    for (int i = threadIdx.x; i < nw; i += blockDim.x)
        mx = fmaxf(mx, fabsf(w[i]));
    __shared__ float red[256];
    red[threadIdx.x] = mx;
    __syncthreads();
    for (int s = 128; s > 0; s >>= 1) {
        if ((int)threadIdx.x < s)
            red[threadIdx.x] = fmaxf(red[threadIdx.x], red[threadIdx.x + s]);
        __syncthreads();
    }
    const float sw = red[0] / 3.0f;

    const int lo = (int)((size_t)nw * SL[bid] / NS[bid]);
    const int hi = (int)((size_t)nw * (SL[bid] + 1) / NS[bid]);

    float* wq = WQ[t];
    for (int i = lo + (int)threadIdx.x; i < hi; i += blockDim.x) {
        float q = rintf(w[i] / sw);
        q = fminf(fmaxf(q, -3.0f), 3.0f);
        const float val = q * sw;
        if (MM[t]) {
            const int m = i / KK[t];
            const int k = i - m * KK[t];
            wq[k * MM[t] + m] = val;
        } else {
            wq[i] = val;
        }
    }
    if (B[t] != nullptr && SL[bid] == 0) {
        const float sb = sw * (SP[t][0] / 15.0f);
        for (int i = threadIdx.x; i < NB[t]; i += blockDim.x)
            BQ[t][i] = rintf(B[t][i] / sb) * sb;
    }
}

// ---------------------------------------------------------------------------
// Fused conv3x3(VALID)+bias+quant_relu+maxpool2, direct-global-read with a
// 3-deep software-pipelined row prefetch: step s issues the loads for step
// s+2 into a 3-slot register ring, then consumes slot s%3 (loaded ~2 compute
// blocks earlier -> vmcnt wait covered by FMAs). All indices compile-time.
// Thread = (cog, xg, ry): NCO output channels x 4 pooled cols x 1 pooled row.
// ---------------------------------------------------------------------------
template<int CIN, int COUT, int NCO, int HIN, int WSIN,
         int HPOOL, int WPOOL, int WSOUT, int XG, int RB,
         int THREADS, bool HAS_BIAS>
__global__ __launch_bounds__(THREADS)
void conv_stage(const float* __restrict__ in,
                const float* __restrict__ qw,
                const float* __restrict__ qb,
                const float* __restrict__ s_act,
                float* __restrict__ out)
{
    constexpr int GROUPS = COUT / NCO;
    constexpr int W4IN   = WSIN / 4;
    constexpr int NW     = COUT * CIN * 9;
    constexpr int STEPS  = 4 * CIN;
    static_assert(NCO * GROUPS == COUT, "NCO divides COUT");
    static_assert(GROUPS * XG * RB <= THREADS, "single compute pass");
    static_assert(4 * XG == WSOUT, "full padded row coverage");
    static_assert(WSIN % 4 == 0, "vec4 loads");

    __shared__ float lw[NW];
    __shared__ float lb[COUT];

    const int r0  = blockIdx.x * RB;
    const int n   = blockIdx.y;
    const int tid = threadIdx.x;

    for (int i = tid; i < NW; i += THREADS) lw[i] = qw[i];
    if (HAS_BIAS)
        for (int i = tid; i < COUT; i += THREADS) lb[i] = qb[i];
    __syncthreads();

    const int o = tid;
    if (o >= GROUPS * XG * RB) return;
    const int cog = o % GROUPS;
    const int xg  = (o / GROUPS) % XG;
    const int ry  = o / (GROUPS * XG);
    const int r   = r0 + ry;
    if (r >= HPOOL) return;

    const float step = s_act[0] / 15.0f;

    // float4 unit offsets within a row (clamped at the right edge; clamped
    // values only feed pooled columns >= WPOOL which are written as 0 pad)
    const int u0 = 2 * xg;
    const int u1 = 2 * xg + 1;
    const int u2 = (2 * xg + 2 < W4IN) ? (2 * xg + 2) : (W4IN - 1);

    // base: channel 0, input row 2r
    const float* base = in + (size_t)n * CIN * HIN * WSIN + (size_t)(2 * r) * WSIN;

    float acc[NCO][16];   // [co][conv-row(2) x 8 conv cols]
#pragma unroll
    for (int j = 0; j < NCO; ++j)
#pragma unroll
        for (int i = 0; i < 16; ++i) acc[j][i] = 0.0f;

    float4 buf[3][3];     // 3-slot prefetch ring
    float  wv[NCO][9];

#define ISSUE_STEP(S)                                                          \
    {                                                                          \
        const float* rp = base + (size_t)((S) >> 2) * HIN * WSIN               \
                               + (size_t)((S) & 3) * WSIN;                     \
        buf[(S) % 3][0] = *(const float4*)&rp[4 * u0];                         \
        buf[(S) % 3][1] = *(const float4*)&rp[4 * u1];                         \
        buf[(S) % 3][2] = *(const float4*)&rp[4 * u2];                         \
    }

    ISSUE_STEP(0);
    ISSUE_STEP(1);

#pragma unroll
    for (int s = 0; s < STEPS; ++s) {
        const int c  = s >> 2;
        const int rr = s & 3;

        if (s + 2 < STEPS) ISSUE_STEP(s + 2);

        if (rr == 0) {
#pragma unroll
            for (int j = 0; j < NCO; ++j)
#pragma unroll
                for (int k = 0; k < 9; ++k)
                    wv[j][k] = lw[((NCO * cog + j) * CIN + c) * 9 + k];
        }

        const float* row = (const float*)buf[s % 3];   // 12 floats

        if (rr < 3) {
#pragma unroll
            for (int j = 0; j < NCO; ++j)
#pragma unroll
                for (int kc = 0; kc < 3; ++kc)
#pragma unroll
                    for (int xx = 0; xx < 8; ++xx)
                        acc[j][xx] = fmaf(row[xx + kc], wv[j][rr * 3 + kc], acc[j][xx]);
        }
        if (rr >= 1) {
#pragma unroll
            for (int j = 0; j < NCO; ++j)
#pragma unroll
                for (int kc = 0; kc < 3; ++kc)
#pragma unroll
                    for (int xx = 0; xx < 8; ++xx)
                        acc[j][8 + xx] = fmaf(row[xx + kc], wv[j][(rr - 1) * 3 + kc], acc[j][8 + xx]);
        }
    }
#undef ISSUE_STEP

#pragma unroll
    for (int j = 0; j < NCO; ++j) {
        const int co = NCO * cog + j;
        const float bias = HAS_BIAS ? lb[co] : 0.0f;
        float4 st;
#pragma unroll
        for (int t = 0; t < 4; ++t) {
            float m = fmaxf(fmaxf(acc[j][2 * t], acc[j][2 * t + 1]),
                            fmaxf(acc[j][8 + 2 * t], acc[j][8 + 2 * t + 1]));
            float v = fmaxf(m + bias, 0.0f);
            float q = rintf(v / step);
            q = fminf(fmaxf(q, 0.0f), 15.0f);
            ((float*)&st)[t] = (4 * xg + t < WPOOL) ? q * step : 0.0f;
        }
        *(float4*)&out[(((size_t)n * COUT + co) * HPOOL + r) * WSOUT + 4 * xg] = st;
    }
}

// ---------------------------------------------------------------------------
// Fused tail: stage4 conv + stage5 conv + fc1 + fc2 + fc3. One block / image.
// ---------------------------------------------------------------------------
__global__ __launch_bounds__(256)
void tail_stage(const float* __restrict__ in3,   // [256][18][18][20]
                const float* __restrict__ ws,
                const float* __restrict__ s4, const float* __restrict__ s5,
                const float* __restrict__ s6, const float* __restrict__ s7,
                float* __restrict__ out)
{
    __shared__ float A[18][18][20];
    __shared__ float W4[2916], W5[2916];
    __shared__ float B4[18], B5[18];
    __shared__ float O4[18][8][8];
    __shared__ float A5[162], A6[120], A7[84];

    const int n   = blockIdx.x;
    const int tid = threadIdx.x;

    const float4* src = (const float4*)(in3 + (size_t)n * 6480);
    float4* dstA = (float4*)&A[0][0][0];
    for (int i = tid; i < 1620; i += 256) dstA[i] = src[i];
    const float* qw4 = ws + OFF_QW4;
    const float* qw5 = ws + OFF_QW5;
    for (int i = tid; i < 2916; i += 256) { W4[i] = qw4[i]; W5[i] = qw5[i]; }
    if (tid < 18) { B4[tid] = (ws + OFF_QB4)[tid]; B5[tid] = (ws + OFF_QB5)[tid]; }
    __syncthreads();

    // ---- stage 4: [18,18,18] -> [18,8,8] ----
    {
        const float step = s4[0] / 15.0f;
        for (int o = tid; o < 18 * 64; o += 256) {
            const int co = o >> 6;
            const int r  = (o >> 3) & 7;
            const int x  = o & 7;
            float a00 = 0.f, a01 = 0.f, a10 = 0.f, a11 = 0.f;
            for (int c = 0; c < 18; ++c) {
                float win[4][4];
#pragma unroll
                for (int rr = 0; rr < 4; ++rr)
#pragma unroll
                    for (int cc = 0; cc < 4; ++cc)
                        win[rr][cc] = A[c][2 * r + rr][2 * x + cc];
                const float* wp = &W4[(co * 18 + c) * 9];
#pragma unroll
                for (int kr = 0; kr < 3; ++kr)
#pragma unroll
                    for (int kc = 0; kc < 3; ++kc) {
                        const float wv = wp[kr * 3 + kc];
                        a00 = fmaf(win[kr    ][kc    ], wv, a00);
                        a01 = fmaf(win[kr    ][kc + 1], wv, a01);
                        a10 = fmaf(win[kr + 1][kc    ], wv, a10);
                        a11 = fmaf(win[kr + 1][kc + 1], wv, a11);
                    }
            }
            float m = fmaxf(fmaxf(a00, a01), fmaxf(a10, a11));
            float v = fmaxf(m + B4[co], 0.0f);
            float q = rintf(v / step);
            q = fminf(fmaxf(q, 0.0f), 15.0f);
            O4[co][r][x] = q * step;
        }
    }
    __syncthreads();

    // ---- stage 5: [18,8,8] -> [18,3,3] = A5[162] ----
    {
        const float step = s5[0] / 15.0f;
        if (tid < 162) {
            const int co = tid / 9;
            const int rem = tid - co * 9;
            const int r = rem / 3;
            const int x = rem - r * 3;
            float a00 = 0.f, a01 = 0.f, a10 = 0.f, a11 = 0.f;
            for (int c = 0; c < 18; ++c) {
                float win[4][4];
#pragma unroll
                for (int rr = 0; rr < 4; ++rr)
#pragma unroll
                    for (int cc = 0; cc < 4; ++cc)
                        win[rr][cc] = O4[c][2 * r + rr][2 * x + cc];
                const float* wp = &W5[(co * 18 + c) * 9];
#pragma unroll
                for (int kr = 0; kr < 3; ++kr)
#pragma unroll
                    for (int kc = 0; kc < 3; ++kc) {
                        const float wv = wp[kr * 3 + kc];
                        a00 = fmaf(win[kr    ][kc    ], wv, a00);
                        a01 = fmaf(win[kr    ][kc + 1], wv, a01);
                        a10 = fmaf(win[kr + 1][kc    ], wv, a10);
                        a11 = fmaf(win[kr + 1][kc + 1], wv, a11);
                    }
            }
            float m = fmaxf(fmaxf(a00, a01), fmaxf(a10, a11));
            float v = fmaxf(m + B5[co], 0.0f);
            float q = rintf(v / step);
            q = fminf(fmaxf(q, 0.0f), 15.0f);
            A5[tid] = q * step;
        }
    }
    __syncthreads();

    // ---- fc1: [162] -> [120], quant s6 ----
    {
        const float* w = ws + OFF_QF1;    // [162][120]
        if (tid < 120) {
            float acc = 0.f;
#pragma unroll 6
            for (int k = 0; k < 162; ++k)
                acc = fmaf(A5[k], w[k * 120 + tid], acc);
            acc += (ws + OFF_QFB1)[tid];
            const float step = s6[0] / 15.0f;
            float q = rintf(fmaxf(acc, 0.0f) / step);
            q = fminf(fmaxf(q, 0.0f), 15.0f);
            A6[tid] = q * step;
        }
    }
    __syncthreads();

    // ---- fc2: [120] -> [84], quant s7 ----
    {
        const float* w = ws + OFF_QF2;    // [120][84]
        if (tid < 84) {
            float acc = 0.f;
#pragma unroll 6
            for (int k = 0; k < 120; ++k)
                acc = fmaf(A6[k], w[k * 84 + tid], acc);
            acc += (ws + OFF_QFB2)[tid];
            const float step = s7[0] / 15.0f;
            float q = rintf(fmaxf(acc, 0.0f) / step);
            q = fminf(fmaxf(q, 0.0f), 15.0f);
            A7[tid] = q * step;
        }
    }
    __syncthreads();

    // ---- fc3: [84] -> [9] ----
    {
        const float* w = ws + OFF_QF3;    // [84][9]
        if (tid < 9) {
            float acc = 0.f;
#pragma unroll 6
            for (int k = 0; k < 84; ++k)
                acc = fmaf(A7[k], w[k * 9 + tid], acc);
            out[(size_t)n * 9 + tid] = acc;
        }
    }
}

// ---------------------------------------------------------------------------
extern "C" void kernel_launch(void* const* d_in, const int* in_sizes, int n_in,
                              void* d_out, int out_size, void* d_ws, size_t ws_size,
                              hipStream_t stream)
{
    const float* x   = (const float*)d_in[0];
    const float* w1  = (const float*)d_in[1];
    const float* w2  = (const float*)d_in[2];
    const float* b2  = (const float*)d_in[3];
    const float* w3  = (const float*)d_in[4];
    const float* b3  = (const float*)d_in[5];
    const float* w4  = (const float*)d_in[6];
    const float* b4  = (const float*)d_in[7];
    const float* w5  = (const float*)d_in[8];
    const float* b5  = (const float*)d_in[9];
    const float* fw1 = (const float*)d_in[10];
    const float* fb1 = (const float*)d_in[11];
    const float* fw2 = (const float*)d_in[12];
    const float* fb2 = (const float*)d_in[13];
    const float* fw3 = (const float*)d_in[14];
    const float* s1  = (const float*)d_in[15];
    const float* s2  = (const float*)d_in[16];
    const float* s3  = (const float*)d_in[17];
    const float* s4  = (const float*)d_in[18];
    const float* s5  = (const float*)d_in[19];
    const float* s6  = (const float*)d_in[20];
    const float* s7  = (const float*)d_in[21];

    float* ws = (float*)d_ws;
    float* out = (float*)d_out;

    quant_prep<<<12, 256, 0, stream>>>(w1, w2, b2, w3, b3, w4, b4, w5, b5,
                                       fw1, fb1, fw2, fb2, fw3,
                                       s1, s2, s3, s4, s5, s6, ws);

    // stage 1: [256,3,160,160] -> [256,6,79,80p]; NCO=2 GROUPS=3 XG=20 RB=4
    conv_stage<3, 6, 2, 160, 160, 79, 79, 80, 20, 4, 256, false>
        <<<dim3(20, 256), 256, 0, stream>>>(x, ws + OFF_QW1, nullptr, s1, ws + OFF_OUT1);

    // stage 2: -> [256,12,38,40p]; NCO=2 GROUPS=6 XG=10 RB=4
    conv_stage<6, 12, 2, 79, 80, 38, 38, 40, 10, 4, 256, true>
        <<<dim3(10, 256), 256, 0, stream>>>(ws + OFF_OUT1, ws + OFF_QW2, ws + OFF_QB2, s2, ws + OFF_OUT2);

    // stage 3: -> [256,18,18,20p]; NCO=3 GROUPS=6 XG=5 RB=6
    conv_stage<12, 18, 3, 38, 40, 18, 18, 20, 5, 6, 192, true>
        <<<dim3(3, 256), 192, 0, stream>>>(ws + OFF_OUT2, ws + OFF_QW3, ws + OFF_QB3, s3, ws + OFF_OUT3);

    // fused tail: stage4 + stage5 + fc1 + fc2 + fc3, one block per image
    tail_stage<<<256, 256, 0, stream>>>(ws + OFF_OUT3, ws, s4, s5, s6, s7, out);
}

// Round 8
// 152.752 us; speedup vs baseline: 4.8012x; 1.3160x over previous
//
#include <hip/hip_runtime.h>
#include <hip/hip_bf16.h>
#include <math.h>

// ---------------------------------------------------------------------------
// Workspace layout (float offsets). Only conv intermediates live in ws now.
// ---------------------------------------------------------------------------
constexpr size_t OFF_OUT1 = 0;                                // [256][6][79][80]
constexpr size_t OFF_OUT2 = (size_t)256 * 6 * 79 * 80;        // [256][12][38][40]

// ---------------------------------------------------------------------------
// Fused conv3x3(VALID)+bias+quant_relu+maxpool2, direct-global-read with a
// 3-deep software-pipelined row prefetch (R7 hot loop, unchanged), plus
// SELF-QUANTIZATION of weights/bias: block computes s = max|w|/3 (exact,
// order-independent reduction -> bit-identical across blocks), quantizes
// into LDS. Removes the separate quant_prep dispatch.
// Thread = (cog, xg, ry): NCO output channels x 4 pooled cols x 1 pooled row.
// ---------------------------------------------------------------------------
template<int CIN, int COUT, int NCO, int HIN, int WSIN,
         int HPOOL, int WPOOL, int WSOUT, int XG, int RB,
         int THREADS, bool HAS_BIAS>
__global__ __launch_bounds__(THREADS)
void conv_stage(const float* __restrict__ in,
                const float* __restrict__ w_raw,
                const float* __restrict__ b_raw,
                const float* __restrict__ s_prev,   // bias scale input (HAS_BIAS)
                const float* __restrict__ s_act,
                float* __restrict__ out)
{
    constexpr int GROUPS = COUT / NCO;
    constexpr int W4IN   = WSIN / 4;
    constexpr int NW     = COUT * CIN * 9;
    constexpr int STEPS  = 4 * CIN;
    static_assert(NCO * GROUPS == COUT, "NCO divides COUT");
    static_assert(GROUPS * XG * RB <= THREADS, "single compute pass");
    static_assert(4 * XG == WSOUT, "full padded row coverage");
    static_assert(WSIN % 4 == 0, "vec4 loads");

    __shared__ float lw[NW];
    __shared__ float lb[COUT];
    __shared__ float red[THREADS];

    const int r0  = blockIdx.x * RB;
    const int n   = blockIdx.y;
    const int tid = threadIdx.x;

    // ---- self-quant: stage raw weights, block max-abs, quantize in place ----
    float mx = 0.0f;
    for (int i = tid; i < NW; i += THREADS) {
        const float v = w_raw[i];
        lw[i] = v;
        mx = fmaxf(mx, fabsf(v));
    }
    if (HAS_BIAS)
        for (int i = tid; i < COUT; i += THREADS) lb[i] = b_raw[i];
    red[tid] = mx;
    __syncthreads();
    for (int s = THREADS / 2; s > 0; s >>= 1) {
        if (tid < s) red[tid] = fmaxf(red[tid], red[tid + s]);
        __syncthreads();
    }
    const float sw_ = red[0] / 3.0f;
    for (int i = tid; i < NW; i += THREADS) {
        float q = rintf(lw[i] / sw_);
        q = fminf(fmaxf(q, -3.0f), 3.0f);
        lw[i] = q * sw_;
    }
    if (HAS_BIAS) {
        const float sb = sw_ * (s_prev[0] / 15.0f);
        for (int i = tid; i < COUT; i += THREADS)
            lb[i] = rintf(lb[i] / sb) * sb;
    }
    __syncthreads();

    const int o = tid;
    if (o >= GROUPS * XG * RB) return;
    const int cog = o % GROUPS;
    const int xg  = (o / GROUPS) % XG;
    const int ry  = o / (GROUPS * XG);
    const int r   = r0 + ry;
    if (r >= HPOOL) return;

    const float step = s_act[0] / 15.0f;

    const int u0 = 2 * xg;
    const int u1 = 2 * xg + 1;
    const int u2 = (2 * xg + 2 < W4IN) ? (2 * xg + 2) : (W4IN - 1);

    const float* base = in + (size_t)n * CIN * HIN * WSIN + (size_t)(2 * r) * WSIN;

    float acc[NCO][16];
#pragma unroll
    for (int j = 0; j < NCO; ++j)
#pragma unroll
        for (int i = 0; i < 16; ++i) acc[j][i] = 0.0f;

    float4 buf[3][3];
    float  wv[NCO][9];

#define ISSUE_STEP(S)                                                          \
    {                                                                          \
        const float* rp = base + (size_t)((S) >> 2) * HIN * WSIN               \
                               + (size_t)((S) & 3) * WSIN;                     \
        buf[(S) % 3][0] = *(const float4*)&rp[4 * u0];                         \
        buf[(S) % 3][1] = *(const float4*)&rp[4 * u1];                         \
        buf[(S) % 3][2] = *(const float4*)&rp[4 * u2];                         \
    }

    ISSUE_STEP(0);
    ISSUE_STEP(1);

#pragma unroll
    for (int s = 0; s < STEPS; ++s) {
        const int c  = s >> 2;
        const int rr = s & 3;

        if (s + 2 < STEPS) ISSUE_STEP(s + 2);

        if (rr == 0) {
#pragma unroll
            for (int j = 0; j < NCO; ++j)
#pragma unroll
                for (int k = 0; k < 9; ++k)
                    wv[j][k] = lw[((NCO * cog + j) * CIN + c) * 9 + k];
        }

        const float* row = (const float*)buf[s % 3];

        if (rr < 3) {
#pragma unroll
            for (int j = 0; j < NCO; ++j)
#pragma unroll
                for (int kc = 0; kc < 3; ++kc)
#pragma unroll
                    for (int xx = 0; xx < 8; ++xx)
                        acc[j][xx] = fmaf(row[xx + kc], wv[j][rr * 3 + kc], acc[j][xx]);
        }
        if (rr >= 1) {
#pragma unroll
            for (int j = 0; j < NCO; ++j)
#pragma unroll
                for (int kc = 0; kc < 3; ++kc)
#pragma unroll
                    for (int xx = 0; xx < 8; ++xx)
                        acc[j][8 + xx] = fmaf(row[xx + kc], wv[j][(rr - 1) * 3 + kc], acc[j][8 + xx]);
        }
    }
#undef ISSUE_STEP

#pragma unroll
    for (int j = 0; j < NCO; ++j) {
        const int co = NCO * cog + j;
        const float bias = HAS_BIAS ? lb[co] : 0.0f;
        float4 st;
#pragma unroll
        for (int t = 0; t < 4; ++t) {
            float m = fmaxf(fmaxf(acc[j][2 * t], acc[j][2 * t + 1]),
                            fmaxf(acc[j][8 + 2 * t], acc[j][8 + 2 * t + 1]));
            float v = fmaxf(m + bias, 0.0f);
            float q = rintf(v / step);
            q = fminf(fmaxf(q, 0.0f), 15.0f);
            ((float*)&st)[t] = (4 * xg + t < WPOOL) ? q * step : 0.0f;
        }
        *(float4*)&out[(((size_t)n * COUT + co) * HPOOL + r) * WSOUT + 4 * xg] = st;
    }
}

// ---------------------------------------------------------------------------
// Mega tail: stage3 + stage4 + stage5 + fc1 + fc2 + fc3, one block per image.
// Stage-3 input slab [12][38][40] (72.9 KB) + all conv weights live in LDS;
// weights self-quantized in-kernel; fc weights quantized on the fly from
// global (L2-resident). ~131 KB static LDS -> 1 block/CU, 256 blocks.
// ---------------------------------------------------------------------------
__global__ __launch_bounds__(512)
void tail_mega(const float* __restrict__ in2,     // ws OUT2 [256][12][38][40]
               const float* __restrict__ w3, const float* __restrict__ b3,
               const float* __restrict__ w4, const float* __restrict__ b4,
               const float* __restrict__ w5, const float* __restrict__ b5,
               const float* __restrict__ fw1, const float* __restrict__ fb1,
               const float* __restrict__ fw2, const float* __restrict__ fb2,
               const float* __restrict__ fw3,
               const float* __restrict__ s2, const float* __restrict__ s3,
               const float* __restrict__ s4, const float* __restrict__ s5,
               const float* __restrict__ s6, const float* __restrict__ s7,
               float* __restrict__ out)
{
    __shared__ float SL[12 * 38 * 40];   // 72960 B  stage-3 input slab
    __shared__ float A3[18 * 18 * 18];   // 23328 B  stage-3 out (aliased as red in phase 0)
    __shared__ float W3q[1944], W4q[2916], W5q[2916];
    __shared__ float B3q[18], B4q[18], B5q[18];
    __shared__ float O4[18 * 8 * 8];     // stage-4 out
    __shared__ float A5[162], A6[120], A7[84];

    const int n   = blockIdx.x;
    const int tid = threadIdx.x;
    float* red = A3;                     // 6*512 = 3072 <= 5832, dead before A3 writes

    // ---- phase 0: slab + raw weights to LDS, max-abs reductions ----
    {
        const float4* src = (const float4*)(in2 + (size_t)n * 18240);
        float4* dst = (float4*)SL;
        for (int i = tid; i < 4560; i += 512) dst[i] = src[i];
    }
    float m3 = 0.f, m4 = 0.f, m5 = 0.f, g1 = 0.f, g2 = 0.f, g3 = 0.f;
    for (int i = tid; i < 1944; i += 512) { const float v = w3[i]; W3q[i] = v; m3 = fmaxf(m3, fabsf(v)); }
    for (int i = tid; i < 2916; i += 512) { const float v = w4[i]; W4q[i] = v; m4 = fmaxf(m4, fabsf(v)); }
    for (int i = tid; i < 2916; i += 512) { const float v = w5[i]; W5q[i] = v; m5 = fmaxf(m5, fabsf(v)); }
    for (int i = tid; i < 19440; i += 512) g1 = fmaxf(g1, fabsf(fw1[i]));
    for (int i = tid; i < 10080; i += 512) g2 = fmaxf(g2, fabsf(fw2[i]));
    for (int i = tid; i <   756; i += 512) g3 = fmaxf(g3, fabsf(fw3[i]));
    if (tid < 18) { B3q[tid] = b3[tid]; B4q[tid] = b4[tid]; B5q[tid] = b5[tid]; }
    red[0 * 512 + tid] = m3; red[1 * 512 + tid] = m4; red[2 * 512 + tid] = m5;
    red[3 * 512 + tid] = g1; red[4 * 512 + tid] = g2; red[5 * 512 + tid] = g3;
    __syncthreads();
    for (int s = 256; s > 0; s >>= 1) {
        if (tid < s)
#pragma unroll
            for (int j = 0; j < 6; ++j)
                red[j * 512 + tid] = fmaxf(red[j * 512 + tid], red[j * 512 + tid + s]);
        __syncthreads();
    }
    const float sw3 = red[0] / 3.0f, sw4 = red[512] / 3.0f, sw5 = red[1024] / 3.0f;
    const float sf1 = red[1536] / 3.0f, sf2 = red[2048] / 3.0f, sf3 = red[2560] / 3.0f;

    for (int i = tid; i < 1944; i += 512) { float q = rintf(W3q[i] / sw3); q = fminf(fmaxf(q, -3.f), 3.f); W3q[i] = q * sw3; }
    for (int i = tid; i < 2916; i += 512) { float q = rintf(W4q[i] / sw4); q = fminf(fmaxf(q, -3.f), 3.f); W4q[i] = q * sw4; }
    for (int i = tid; i < 2916; i += 512) { float q = rintf(W5q[i] / sw5); q = fminf(fmaxf(q, -3.f), 3.f); W5q[i] = q * sw5; }
    if (tid < 18) {
        const float sb3 = sw3 * (s2[0] / 15.0f); B3q[tid] = rintf(B3q[tid] / sb3) * sb3;
        const float sb4 = sw4 * (s3[0] / 15.0f); B4q[tid] = rintf(B4q[tid] / sb4) * sb4;
        const float sb5 = sw5 * (s4[0] / 15.0f); B5q[tid] = rintf(B5q[tid] / sb5) * sb5;
    }
    __syncthreads();

    // ---- phase 1: stage3 [12,38,38]->[18,18,18] (pool). item=(r,co,third) so
    // lanes share r: SL row reads are <=6 distinct addrs/wave (broadcast). ----
    {
        const float st = s3[0] / 15.0f;
        for (int it = tid; it < 972; it += 512) {
            const int r  = it / 54;
            const int rm = it - r * 54;
            const int co = rm / 3;
            const int th = rm - co * 3;        // pooled x in [6*th, 6*th+6)

            float acc0[12], acc1[12];
#pragma unroll
            for (int i = 0; i < 12; ++i) { acc0[i] = 0.f; acc1[i] = 0.f; }

            for (int c = 0; c < 12; ++c) {
                float wv[9];
#pragma unroll
                for (int k = 0; k < 9; ++k) wv[k] = W3q[(co * 12 + c) * 9 + k];
#pragma unroll
                for (int rr = 0; rr < 4; ++rr) {
                    const float* rp = &SL[(c * 38 + 2 * r + rr) * 40 + 12 * th];
                    float row[14];
#pragma unroll
                    for (int v = 0; v < 7; ++v)
                        *(float2*)&row[2 * v] = *(const float2*)&rp[2 * v];
                    if (rr < 3) {
#pragma unroll
                        for (int kc = 0; kc < 3; ++kc)
#pragma unroll
                            for (int xx = 0; xx < 12; ++xx)
                                acc0[xx] = fmaf(row[xx + kc], wv[rr * 3 + kc], acc0[xx]);
                    }
                    if (rr >= 1) {
#pragma unroll
                        for (int kc = 0; kc < 3; ++kc)
#pragma unroll
                            for (int xx = 0; xx < 12; ++xx)
                                acc1[xx] = fmaf(row[xx + kc], wv[(rr - 1) * 3 + kc], acc1[xx]);
                    }
                }
            }
            const float bias = B3q[co];
#pragma unroll
            for (int x = 0; x < 6; ++x) {
                float m = fmaxf(fmaxf(acc0[2 * x], acc0[2 * x + 1]),
                                fmaxf(acc1[2 * x], acc1[2 * x + 1]));
                float v = fmaxf(m + bias, 0.0f);
                float q = rintf(v / st);
                q = fminf(fmaxf(q, 0.0f), 15.0f);
                A3[(co * 18 + r) * 18 + 6 * th + x] = q * st;
            }
        }
    }
    __syncthreads();

    // ---- phase 2: stage4 [18,18,18]->[18,8,8] ----
    {
        const float st = s4[0] / 15.0f;
        for (int o = tid; o < 1152; o += 512) {
            const int co = o >> 6;
            const int r  = (o >> 3) & 7;
            const int x  = o & 7;
            float a00 = 0.f, a01 = 0.f, a10 = 0.f, a11 = 0.f;
            for (int c = 0; c < 18; ++c) {
                float win[4][4];
#pragma unroll
                for (int rr = 0; rr < 4; ++rr) {
                    const int base = (c * 18 + 2 * r + rr) * 18 + 2 * x;
                    *(float2*)&win[rr][0] = *(const float2*)&A3[base];
                    *(float2*)&win[rr][2] = *(const float2*)&A3[base + 2];
                }
                const float* wp = &W4q[(co * 18 + c) * 9];
#pragma unroll
                for (int kr = 0; kr < 3; ++kr)
#pragma unroll
                    for (int kc = 0; kc < 3; ++kc) {
                        const float wv = wp[kr * 3 + kc];
                        a00 = fmaf(win[kr    ][kc    ], wv, a00);
                        a01 = fmaf(win[kr    ][kc + 1], wv, a01);
                        a10 = fmaf(win[kr + 1][kc    ], wv, a10);
                        a11 = fmaf(win[kr + 1][kc + 1], wv, a11);
                    }
            }
            float m = fmaxf(fmaxf(a00, a01), fmaxf(a10, a11));
            float v = fmaxf(m + B4q[co], 0.0f);
            float q = rintf(v / st);
            q = fminf(fmaxf(q, 0.0f), 15.0f);
            O4[o] = q * st;                  // layout (co, r, x)
        }
    }
    __syncthreads();

    // ---- phase 3: stage5 [18,8,8]->[18,3,3] = A5[162] ----
    {
        const float st = s5[0] / 15.0f;
        if (tid < 162) {
            const int co  = tid / 9;
            const int rem = tid - co * 9;
            const int r   = rem / 3;
            const int x   = rem - r * 3;
            float a00 = 0.f, a01 = 0.f, a10 = 0.f, a11 = 0.f;
            for (int c = 0; c < 18; ++c) {
                float win[4][4];
#pragma unroll
                for (int rr = 0; rr < 4; ++rr) {
                    const int base = c * 64 + (2 * r + rr) * 8 + 2 * x;
                    *(float2*)&win[rr][0] = *(const float2*)&O4[base];
                    *(float2*)&win[rr][2] = *(const float2*)&O4[base + 2];
                }
                const float* wp = &W5q[(co * 18 + c) * 9];
#pragma unroll
                for (int kr = 0; kr < 3; ++kr)
#pragma unroll
                    for (int kc = 0; kc < 3; ++kc) {
                        const float wv = wp[kr * 3 + kc];
                        a00 = fmaf(win[kr    ][kc    ], wv, a00);
                        a01 = fmaf(win[kr    ][kc + 1], wv, a01);
                        a10 = fmaf(win[kr + 1][kc    ], wv, a10);
                        a11 = fmaf(win[kr + 1][kc + 1], wv, a11);
                    }
            }
            float m = fmaxf(fmaxf(a00, a01), fmaxf(a10, a11));
            float v = fmaxf(m + B5q[co], 0.0f);
            float q = rintf(v / st);
            q = fminf(fmaxf(q, 0.0f), 15.0f);
            A5[tid] = q * st;                // (co, r, x) = reference reshape order
        }
    }
    __syncthreads();

    // ---- fc1: [162]->[120], on-the-fly weight quant ----
    if (tid < 120) {
        float acc = 0.f;
        const float* wr = fw1 + (size_t)tid * 162;
#pragma unroll 6
        for (int k = 0; k < 162; ++k) {
            float q = rintf(wr[k] / sf1);
            q = fminf(fmaxf(q, -3.f), 3.f);
            acc = fmaf(A5[k], q * sf1, acc);
        }
        const float sb = sf1 * (s5[0] / 15.0f);
        acc += rintf(fb1[tid] / sb) * sb;
        const float st = s6[0] / 15.0f;
        float q = rintf(fmaxf(acc, 0.0f) / st);
        q = fminf(fmaxf(q, 0.0f), 15.0f);
        A6[tid] = q * st;
    }
    __syncthreads();

    // ---- fc2: [120]->[84] ----
    if (tid < 84) {
        float acc = 0.f;
        const float* wr = fw2 + (size_t)tid * 120;
#pragma unroll 6
        for (int k = 0; k < 120; ++k) {
            float q = rintf(wr[k] / sf2);
            q = fminf(fmaxf(q, -3.f), 3.f);
            acc = fmaf(A6[k], q * sf2, acc);
        }
        const float sb = sf2 * (s6[0] / 15.0f);
        acc += rintf(fb2[tid] / sb) * sb;
        const float st = s7[0] / 15.0f;
        float q = rintf(fmaxf(acc, 0.0f) / st);
        q = fminf(fmaxf(q, 0.0f), 15.0f);
        A7[tid] = q * st;
    }
    __syncthreads();

    // ---- fc3: [84]->[9] (no bias, no quant) ----
    if (tid < 9) {
        float acc = 0.f;
        const float* wr = fw3 + (size_t)tid * 84;
#pragma unroll 6
        for (int k = 0; k < 84; ++k) {
            float q = rintf(wr[k] / sf3);
            q = fminf(fmaxf(q, -3.f), 3.f);
            acc = fmaf(A7[k], q * sf3, acc);
        }
        out[(size_t)n * 9 + tid] = acc;
    }
}

// ---------------------------------------------------------------------------
extern "C" void kernel_launch(void* const* d_in, const int* in_sizes, int n_in,
                              void* d_out, int out_size, void* d_ws, size_t ws_size,
                              hipStream_t stream)
{
    const float* x   = (const float*)d_in[0];
    const float* w1  = (const float*)d_in[1];
    const float* w2  = (const float*)d_in[2];
    const float* b2  = (const float*)d_in[3];
    const float* w3  = (const float*)d_in[4];
    const float* b3  = (const float*)d_in[5];
    const float* w4  = (const float*)d_in[6];
    const float* b4  = (const float*)d_in[7];
    const float* w5  = (const float*)d_in[8];
    const float* b5  = (const float*)d_in[9];
    const float* fw1 = (const float*)d_in[10];
    const float* fb1 = (const float*)d_in[11];
    const float* fw2 = (const float*)d_in[12];
    const float* fb2 = (const float*)d_in[13];
    const float* fw3 = (const float*)d_in[14];
    const float* s1  = (const float*)d_in[15];
    const float* s2  = (const float*)d_in[16];
    const float* s3  = (const float*)d_in[17];
    const float* s4  = (const float*)d_in[18];
    const float* s5  = (const float*)d_in[19];
    const float* s6  = (const float*)d_in[20];
    const float* s7  = (const float*)d_in[21];

    float* ws = (float*)d_ws;
    float* out = (float*)d_out;

    // stage 1: [256,3,160,160] -> [256,6,79,80p]; NCO=2 GROUPS=3 XG=20 RB=4
    conv_stage<3, 6, 2, 160, 160, 79, 79, 80, 20, 4, 256, false>
        <<<dim3(20, 256), 256, 0, stream>>>(x, w1, nullptr, nullptr, s1, ws + OFF_OUT1);

    // stage 2: -> [256,12,38,40p]; NCO=2 GROUPS=6 XG=10 RB=4
    conv_stage<6, 12, 2, 79, 80, 38, 38, 40, 10, 4, 256, true>
        <<<dim3(10, 256), 256, 0, stream>>>(ws + OFF_OUT1, w2, b2, s1, s2, ws + OFF_OUT2);

    // mega tail: stage3 + stage4 + stage5 + fc1 + fc2 + fc3, 1 block / image
    tail_mega<<<256, 512, 0, stream>>>(ws + OFF_OUT2,
                                       w3, b3, w4, b4, w5, b5,
                                       fw1, fb1, fw2, fb2, fw3,
                                       s2, s3, s4, s5, s6, s7, out);
}